// Round 1
// baseline (268.098 us; speedup 1.0000x reference)
//
#include <hip/hip_runtime.h>

#define BB 4
#define NN 256
#define DD 256
#define HH 256
#define NEGV -1.0e9f

typedef _Float16 half8 __attribute__((ext_vector_type(8)));
typedef __fp16   fp16x2 __attribute__((ext_vector_type(2)));
typedef float floatx4 __attribute__((ext_vector_type(4)));

// ---------------- prep (split-K x4): S/T partial projections + wconv -----------
// Grid (512, 4): block (g, kk) -> rows 2g..2g+1, d in [kk*64, kk*64+64).
// R20: kk 2->4 doubles resident waves/CU (prep is latency-bound on strided W1
// L2 loads); 4 fp32 atomic addends per output, order-independent to ~1e-7.
// Wst layout (R13 map): [ks][hgrp][q][cc][e] halves; converted when kk==0,g<256.
__global__ __launch_bounds__(256) void prep_split(const float* __restrict__ X,
                                                  const float* __restrict__ W1,
                                                  float* __restrict__ S,
                                                  float* __restrict__ T,
                                                  _Float16* __restrict__ Wst) {
  const int g  = blockIdx.x;   // 0..511
  const int kk = blockIdx.y;   // 0..3
  const int h  = threadIdx.x;  // 0..255

  if (kk == 0 && g < 256) {    // weight conversion for d = g
    const float wcv = W1[(size_t)(2 * DD + g) * HH + h];
    const float wdv = W1[(size_t)(3 * DD + g) * HH + h];
    const int ks = g >> 4;
    const int dd = g & 15;
    const int q  = dd >> 2;
    const int e  = (dd & 3) * 2;
    const int hgrp = h >> 4;
    const int ccw  = h & 15;
    _Float16* p = Wst + ((size_t)((ks * 16 + hgrp) * 4 + q) * 16 + ccw) * 8 + e;
    p[0] = (_Float16)wcv;
    p[1] = (_Float16)wdv;
  }

  const int row0 = g * 2;
  const int dbase = kk * 64;
  __shared__ float xr[2][64];
  if (h < 64)       xr[0][h]      = X[(size_t)row0 * DD + dbase + h];
  else if (h < 128) xr[1][h - 64] = X[(size_t)(row0 + 1) * DD + dbase + (h - 64)];
  __syncthreads();

  const float* __restrict__ Wa = W1 + (size_t)dbase * HH;
  const float* __restrict__ Wb = W1 + (size_t)(DD + dbase) * HH;
  float sa0 = 0.f, sa1 = 0.f, sb0 = 0.f, sb1 = 0.f;
#pragma unroll 8
  for (int d = 0; d < 64; ++d) {
    const float wa = Wa[(size_t)d * HH + h];
    const float wb = Wb[(size_t)d * HH + h];
    sa0 = fmaf(xr[0][d], wa, sa0);  sb0 = fmaf(xr[0][d], wb, sb0);
    sa1 = fmaf(xr[1][d], wa, sa1);  sb1 = fmaf(xr[1][d], wb, sb1);
  }
  atomicAdd(&S[(size_t)(row0 + 0) * HH + h], sa0);
  atomicAdd(&T[(size_t)(row0 + 0) * HH + h], sb0);
  atomicAdd(&S[(size_t)(row0 + 1) * HH + h], sa1);
  atomicAdd(&T[(size_t)(row0 + 1) * HH + h], sb1);
}

__device__ __forceinline__ half8 make_afrag(const float4 xi, const float4 xj) {
  fp16x2 p0 = __builtin_amdgcn_cvt_pkrtz(__builtin_fabsf(xi.x - xj.x), xi.x * xj.x);
  fp16x2 p1 = __builtin_amdgcn_cvt_pkrtz(__builtin_fabsf(xi.y - xj.y), xi.y * xj.y);
  fp16x2 p2 = __builtin_amdgcn_cvt_pkrtz(__builtin_fabsf(xi.z - xj.z), xi.z * xj.z);
  fp16x2 p3 = __builtin_amdgcn_cvt_pkrtz(__builtin_fabsf(xi.w - xj.w), xi.w * xj.w);
  uint4 u;
  u.x = __builtin_bit_cast(unsigned int, p0);
  u.y = __builtin_bit_cast(unsigned int, p1);
  u.z = __builtin_bit_cast(unsigned int, p2);
  u.w = __builtin_bit_cast(unsigned int, p3);
  return __builtin_bit_cast(half8, u);
}

#define MFMA16(af, bf, acc) acc = __builtin_amdgcn_mfma_f32_16x16x32_f16(af, bf, acc, 0, 0, 0)

// ---------------- score: SYMMETRY-PRUNED pair tiles (R18 structure) ------------
// R20: launch_bounds (256,2)->(256,4). LDS 37888*4=151552<=160K, VGPR 112<=128:
// 4 blocks/CU now co-resident (occupancy 19%->~40%) to hide L2 latency of the
// Wst prefetch in the K-loop and the T/S row loads + exp chains in the epilogue.
__global__ __launch_bounds__(256, 4) void score_mfma(
    const float* __restrict__ X,  const float* __restrict__ b1,
    const float* __restrict__ W2, const float* __restrict__ b2,
    const float* __restrict__ S,  const float* __restrict__ T,
    const _Float16* __restrict__ Wst, float* __restrict__ Sc) {

  const int beta = blockIdx.x;      // 0..639
  const int b    = blockIdx.y;
  int i, qt;
  if (beta < 256)      { i = beta >> 2;                    qt = beta & 3; }
  else if (beta < 448) { const int g = beta - 256; const int d3 = g / 3;
                         i = 64 + d3;                      qt = 1 + (g - 3 * d3); }
  else if (beta < 576) { const int g = beta - 448;
                         i = 128 + (g >> 1);               qt = 2 + (g & 1); }
  else                 { i = 192 + (beta - 576);           qt = 3; }
  const int bi    = b * NN + i;
  const int jbase = qt * 64;
  const int isUp  = qt > (i >> 6);  // block-uniform

  const int t     = threadIdx.x;
  const int lane  = t & 63;
  const int hg    = t >> 6;         // 0..3
  const int q     = lane >> 4;
  const int cc    = lane & 15;

  __shared__ __align__(16) float    xi_s[DD];
  __shared__ __align__(16) _Float16 Af[16384];   // 32 KB: [ksl 0..7][jg][q][cc][e]
  __shared__ float pre_s[HH];       // S_i + b1
  __shared__ float pre2_s[HH];      // T_i + b1 (mirror)
  __shared__ float w2_s[HH];
  __shared__ float sc_s[4][64];

  xi_s[t]   = X[(size_t)bi * DD + t];
  pre_s[t]  = S[(size_t)bi * HH + t] + b1[t];
  pre2_s[t] = T[(size_t)bi * HH + t] + b1[t];
  w2_s[t]   = W2[t];

  const float* __restrict__ Tb = T + (size_t)b * NN * HH;
  const float* __restrict__ Sb = S + (size_t)b * NN * HH;

  const int jloc = t & 63;
  const int jg   = jloc >> 4;
  const int ccw  = jloc & 15;
  const float* __restrict__ xjrow = X + (size_t)(b * NN + jbase + jloc) * DD;

  const char* __restrict__ bsrc = (const char*)Wst + hg * 4096 + (size_t)lane * 16;

  floatx4 a00 = (floatx4)0.f, a01 = (floatx4)0.f, a02 = (floatx4)0.f, a03 = (floatx4)0.f;
  floatx4 a10 = (floatx4)0.f, a11 = (floatx4)0.f, a12 = (floatx4)0.f, a13 = (floatx4)0.f;
  floatx4 a20 = (floatx4)0.f, a21 = (floatx4)0.f, a22 = (floatx4)0.f, a23 = (floatx4)0.f;
  floatx4 a30 = (floatx4)0.f, a31 = (floatx4)0.f, a32 = (floatx4)0.f, a33 = (floatx4)0.f;

#pragma unroll 1
  for (int half = 0; half < 2; ++half) {
    __syncthreads();                 // header ready / prior Af reads done

#pragma unroll
    for (int idx = 0; idx < 8; ++idx) {
      const int ksq = (t >> 6) * 8 + idx;       // local 0..31
      const int d0  = (half * 32 + ksq) * 4;
      const int ksl = ksq >> 2;
      const int qw  = ksq & 3;
      const float4 xi4 = *(const float4*)&xi_s[d0];
      const float4 xj4 = *(const float4*)(xjrow + d0);
      *(half8*)&Af[(ksl * 16 + jg * 4 + qw) * 128 + ccw * 8] = make_afrag(xi4, xj4);
    }
    __syncthreads();                 // Af ready; K-loop below is barrier-free

    const char* bk0 = bsrc + (half * 8) * 16384;
    half8 nb0 = *(const half8*)(bk0);
    half8 nb1 = *(const half8*)(bk0 + 1024);
    half8 nb2 = *(const half8*)(bk0 + 2048);
    half8 nb3 = *(const half8*)(bk0 + 3072);
    const _Float16* ap0 = &Af[lane * 8];
    half8 na0 = *(const half8*)(ap0);
    half8 na1 = *(const half8*)(ap0 + 512);
    half8 na2 = *(const half8*)(ap0 + 1024);
    half8 na3 = *(const half8*)(ap0 + 1536);

#pragma unroll
    for (int ksl = 0; ksl < 8; ++ksl) {
      const half8 cb0 = nb0, cb1 = nb1, cb2 = nb2, cb3 = nb3;
      const half8 ca0 = na0, ca1 = na1, ca2 = na2, ca3 = na3;
      if (ksl < 7) {
        const char* bk = bsrc + (half * 8 + ksl + 1) * 16384;
        nb0 = *(const half8*)(bk);
        nb1 = *(const half8*)(bk + 1024);
        nb2 = *(const half8*)(bk + 2048);
        nb3 = *(const half8*)(bk + 3072);
        const _Float16* ap = &Af[(ksl + 1) * 2048 + lane * 8];
        na0 = *(const half8*)(ap);
        na1 = *(const half8*)(ap + 512);
        na2 = *(const half8*)(ap + 1024);
        na3 = *(const half8*)(ap + 1536);
      }
      MFMA16(ca0, cb0, a00); MFMA16(ca0, cb1, a01); MFMA16(ca0, cb2, a02); MFMA16(ca0, cb3, a03);
      MFMA16(ca1, cb0, a10); MFMA16(ca1, cb1, a11); MFMA16(ca1, cb2, a12); MFMA16(ca1, cb3, a13);
      MFMA16(ca2, cb0, a20); MFMA16(ca2, cb1, a21); MFMA16(ca2, cb2, a22); MFMA16(ca2, cb3, a23);
      MFMA16(ca3, cb0, a30); MFMA16(ca3, cb1, a31); MFMA16(ca3, cb2, a32); MFMA16(ca3, cb3, a33);
    }
  }

  // ---- direct epilogue: H = C + (S_i+b1) + T_j ; silu ; dot w2 ----
  float p00, p01, p02, p03, p10, p11, p12, p13;
  float p20, p21, p22, p23, p30, p31, p32, p33;
  p00=p01=p02=p03=p10=p11=p12=p13=0.f;
  p20=p21=p22=p23=p30=p31=p32=p33=0.f;

#define SILU_DOT(A, r, VROW, PREV, P) { \
    const float tv = VROW[(size_t)(jbase + jj16 + q * 4 + r) * HH + h]; \
    const float hv = A[r] + PREV + tv; \
    const float sv = hv * __builtin_amdgcn_rcpf(1.f + __expf(-hv)); \
    P = fmaf(sv, w2v, P); }

#define EPI_HH(hh, A0, A1, A2, A3, VROW, PRE) { \
    const int h = hg * 64 + hh * 16 + cc; \
    const float w2v = w2_s[h]; \
    const float pv  = PRE[h]; \
    { const int jj16 = 0;  SILU_DOT(A0, 0, VROW, pv, p00) SILU_DOT(A0, 1, VROW, pv, p01) \
                           SILU_DOT(A0, 2, VROW, pv, p02) SILU_DOT(A0, 3, VROW, pv, p03) } \
    { const int jj16 = 16; SILU_DOT(A1, 0, VROW, pv, p10) SILU_DOT(A1, 1, VROW, pv, p11) \
                           SILU_DOT(A1, 2, VROW, pv, p12) SILU_DOT(A1, 3, VROW, pv, p13) } \
    { const int jj16 = 32; SILU_DOT(A2, 0, VROW, pv, p20) SILU_DOT(A2, 1, VROW, pv, p21) \
                           SILU_DOT(A2, 2, VROW, pv, p22) SILU_DOT(A2, 3, VROW, pv, p23) } \
    { const int jj16 = 48; SILU_DOT(A3, 0, VROW, pv, p30) SILU_DOT(A3, 1, VROW, pv, p31) \
                           SILU_DOT(A3, 2, VROW, pv, p32) SILU_DOT(A3, 3, VROW, pv, p33) } }

#define REDW(P, jj, r) { \
    float v = P; \
    v += __shfl_xor(v, 1); v += __shfl_xor(v, 2); \
    v += __shfl_xor(v, 4); v += __shfl_xor(v, 8); \
    if (cc == 0) sc_s[hg][jj * 16 + q * 4 + r] = v; }

#define REDW_ALL \
  REDW(p00, 0, 0) REDW(p01, 0, 1) REDW(p02, 0, 2) REDW(p03, 0, 3) \
  REDW(p10, 1, 0) REDW(p11, 1, 1) REDW(p12, 1, 2) REDW(p13, 1, 3) \
  REDW(p20, 2, 0) REDW(p21, 2, 1) REDW(p22, 2, 2) REDW(p23, 2, 3) \
  REDW(p30, 3, 0) REDW(p31, 3, 1) REDW(p32, 3, 2) REDW(p33, 3, 3)

  EPI_HH(0, a00, a10, a20, a30, Tb, pre_s)
  EPI_HH(1, a01, a11, a21, a31, Tb, pre_s)
  EPI_HH(2, a02, a12, a22, a32, Tb, pre_s)
  EPI_HH(3, a03, a13, a23, a33, Tb, pre_s)
  REDW_ALL
  __syncthreads();

  if (t < 64) {
    float s = sc_s[0][t] + sc_s[1][t] + sc_s[2][t] + sc_s[3][t] + b2[0];
    const int jg2 = jbase + t;
    if (jg2 == i) s = NEGV;
    Sc[(size_t)bi * NN + jg2] = s;
  }

  // ---- mirror epilogue (pure-upper blocks): H' = C + S_j + (T_i+b1) ----
  if (isUp) {
    __syncthreads();                 // sc_s reads done before overwrite
    p00=p01=p02=p03=p10=p11=p12=p13=0.f;
    p20=p21=p22=p23=p30=p31=p32=p33=0.f;
    EPI_HH(0, a00, a10, a20, a30, Sb, pre2_s)
    EPI_HH(1, a01, a11, a21, a31, Sb, pre2_s)
    EPI_HH(2, a02, a12, a22, a32, Sb, pre2_s)
    EPI_HH(3, a03, a13, a23, a33, Sb, pre2_s)
    REDW_ALL
    __syncthreads();
    if (t < 64) {
      const float s = sc_s[0][t] + sc_s[1][t] + sc_s[2][t] + sc_s[3][t] + b2[0];
      Sc[(size_t)(b * NN + jbase + t) * NN + i] = s;   // Sc[j, i]
    }
  }
}

// ---------------- softmax: 1 wave per row, barrier-free (R20) ------------------
// 4 rows/block, float4 load/store, 6+6 shfl_xor reductions, no LDS, no syncs.
__global__ __launch_bounds__(256) void softmax_kernel(const float* __restrict__ Sc,
                                                      float* __restrict__ out) {
  const int w    = threadIdx.x >> 6;        // wave 0..3
  const int lane = threadIdx.x & 63;
  const int bi   = blockIdx.x * 4 + w;      // row 0..1023
  const float4 v = *(const float4*)&Sc[(size_t)bi * NN + lane * 4];
  float m = fmaxf(fmaxf(v.x, v.y), fmaxf(v.z, v.w));
  m = fmaxf(m, __shfl_xor(m, 1));  m = fmaxf(m, __shfl_xor(m, 2));
  m = fmaxf(m, __shfl_xor(m, 4));  m = fmaxf(m, __shfl_xor(m, 8));
  m = fmaxf(m, __shfl_xor(m, 16)); m = fmaxf(m, __shfl_xor(m, 32));
  const float e0 = __expf(v.x - m), e1 = __expf(v.y - m);
  const float e2 = __expf(v.z - m), e3 = __expf(v.w - m);
  float sum = (e0 + e1) + (e2 + e3);
  sum += __shfl_xor(sum, 1);  sum += __shfl_xor(sum, 2);
  sum += __shfl_xor(sum, 4);  sum += __shfl_xor(sum, 8);
  sum += __shfl_xor(sum, 16); sum += __shfl_xor(sum, 32);
  const float r = 1.f / sum;
  float4 o; o.x = e0 * r; o.y = e1 * r; o.z = e2 * r; o.w = e3 * r;
  *(float4*)&out[(size_t)bi * NN + lane * 4] = o;
}

extern "C" void kernel_launch(void* const* d_in, const int* in_sizes, int n_in,
                              void* d_out, int out_size, void* d_ws, size_t ws_size,
                              hipStream_t stream) {
  const float* X  = (const float*)d_in[0];
  const float* W1 = (const float*)d_in[1];
  const float* b1 = (const float*)d_in[2];
  const float* W2 = (const float*)d_in[3];
  const float* b2 = (const float*)d_in[4];
  float* out = (float*)d_out;

  float*     Sws = (float*)d_ws;                             // 1 MB
  float*     Tws = Sws + (size_t)BB * NN * HH;               // 1 MB
  _Float16*  Wst = (_Float16*)(Tws + (size_t)BB * NN * HH);  // 256 KB
  float*     Scw = (float*)(Wst + (size_t)16 * HH * 32);     // 1 MB

  // zero S/T for split-K atomic accumulation (stream op — graph-capture safe)
  hipMemsetAsync(Sws, 0, (size_t)2 * BB * NN * HH * sizeof(float), stream);

  prep_split<<<dim3(512, 4), 256, 0, stream>>>(X, W1, Sws, Tws, Wst);
  score_mfma<<<dim3(640, BB), 256, 0, stream>>>(X, b1, W2, b2, Sws, Tws, Wst, Scw);
  softmax_kernel<<<BB * NN / 4, 256, 0, stream>>>(Scw, out);
}

// Round 2
// 204.687 us; speedup vs baseline: 1.3098x; 1.3098x over previous
//
#include <hip/hip_runtime.h>

#define BB 4
#define NN 256
#define DD 256
#define HH 256
#define NEGV -1.0e9f

typedef _Float16 half8 __attribute__((ext_vector_type(8)));
typedef __fp16   fp16x2 __attribute__((ext_vector_type(2)));
typedef float floatx4 __attribute__((ext_vector_type(4)));

// ---------------- prep (split-K x4): S/T partial projections + wconv -----------
// Grid (512, 4): block (g, kk) -> rows 2g..2g+1, d in [kk*64, kk*64+64).
// 4 fp32 atomic addends per output, order-independent to ~1e-7.
// Wst layout (R13 map): [ks][hgrp][q][cc][e] halves; converted when kk==0,g<256.
__global__ __launch_bounds__(256) void prep_split(const float* __restrict__ X,
                                                  const float* __restrict__ W1,
                                                  float* __restrict__ S,
                                                  float* __restrict__ T,
                                                  _Float16* __restrict__ Wst) {
  const int g  = blockIdx.x;   // 0..511
  const int kk = blockIdx.y;   // 0..3
  const int h  = threadIdx.x;  // 0..255

  if (kk == 0 && g < 256) {    // weight conversion for d = g
    const float wcv = W1[(size_t)(2 * DD + g) * HH + h];
    const float wdv = W1[(size_t)(3 * DD + g) * HH + h];
    const int ks = g >> 4;
    const int dd = g & 15;
    const int q  = dd >> 2;
    const int e  = (dd & 3) * 2;
    const int hgrp = h >> 4;
    const int ccw  = h & 15;
    _Float16* p = Wst + ((size_t)((ks * 16 + hgrp) * 4 + q) * 16 + ccw) * 8 + e;
    p[0] = (_Float16)wcv;
    p[1] = (_Float16)wdv;
  }

  const int row0 = g * 2;
  const int dbase = kk * 64;
  __shared__ float xr[2][64];
  if (h < 64)       xr[0][h]      = X[(size_t)row0 * DD + dbase + h];
  else if (h < 128) xr[1][h - 64] = X[(size_t)(row0 + 1) * DD + dbase + (h - 64)];
  __syncthreads();

  const float* __restrict__ Wa = W1 + (size_t)dbase * HH;
  const float* __restrict__ Wb = W1 + (size_t)(DD + dbase) * HH;
  float sa0 = 0.f, sa1 = 0.f, sb0 = 0.f, sb1 = 0.f;
#pragma unroll 8
  for (int d = 0; d < 64; ++d) {
    const float wa = Wa[(size_t)d * HH + h];
    const float wb = Wb[(size_t)d * HH + h];
    sa0 = fmaf(xr[0][d], wa, sa0);  sb0 = fmaf(xr[0][d], wb, sb0);
    sa1 = fmaf(xr[1][d], wa, sa1);  sb1 = fmaf(xr[1][d], wb, sb1);
  }
  atomicAdd(&S[(size_t)(row0 + 0) * HH + h], sa0);
  atomicAdd(&T[(size_t)(row0 + 0) * HH + h], sb0);
  atomicAdd(&S[(size_t)(row0 + 1) * HH + h], sa1);
  atomicAdd(&T[(size_t)(row0 + 1) * HH + h], sb1);
}

__device__ __forceinline__ half8 make_afrag(const float4 xi, const float4 xj) {
  fp16x2 p0 = __builtin_amdgcn_cvt_pkrtz(__builtin_fabsf(xi.x - xj.x), xi.x * xj.x);
  fp16x2 p1 = __builtin_amdgcn_cvt_pkrtz(__builtin_fabsf(xi.y - xj.y), xi.y * xj.y);
  fp16x2 p2 = __builtin_amdgcn_cvt_pkrtz(__builtin_fabsf(xi.z - xj.z), xi.z * xj.z);
  fp16x2 p3 = __builtin_amdgcn_cvt_pkrtz(__builtin_fabsf(xi.w - xj.w), xi.w * xj.w);
  uint4 u;
  u.x = __builtin_bit_cast(unsigned int, p0);
  u.y = __builtin_bit_cast(unsigned int, p1);
  u.z = __builtin_bit_cast(unsigned int, p2);
  u.w = __builtin_bit_cast(unsigned int, p3);
  return __builtin_bit_cast(half8, u);
}

#define MFMA16(af, bf, acc) acc = __builtin_amdgcn_mfma_f32_16x16x32_f16(af, bf, acc, 0, 0, 0)

// ---------------- score: SYMMETRY-PRUNED pair tiles (R18 structure) ------------
// R21: launch_bounds (256,3). Unified regfile math: 112 arch VGPR + 64 AGPR acc
// = 176 total -> only 2 waves/SIMD resident (round-0 occupancy 19%). Cap for
// 3 waves/SIMD is ~168 (8 short of natural -> allocator shaves w/o real spill);
// cap for 4 waves is 128 (48 short -> round-1 spilled 544 MB scratch, 2x slower).
// LDS 3*37888=113K <= 160K. Expect occupancy ~28%, MfmaUtil ~24, score ~80us.
__global__ __launch_bounds__(256, 3) void score_mfma(
    const float* __restrict__ X,  const float* __restrict__ b1,
    const float* __restrict__ W2, const float* __restrict__ b2,
    const float* __restrict__ S,  const float* __restrict__ T,
    const _Float16* __restrict__ Wst, float* __restrict__ Sc) {

  const int beta = blockIdx.x;      // 0..639
  const int b    = blockIdx.y;
  int i, qt;
  if (beta < 256)      { i = beta >> 2;                    qt = beta & 3; }
  else if (beta < 448) { const int g = beta - 256; const int d3 = g / 3;
                         i = 64 + d3;                      qt = 1 + (g - 3 * d3); }
  else if (beta < 576) { const int g = beta - 448;
                         i = 128 + (g >> 1);               qt = 2 + (g & 1); }
  else                 { i = 192 + (beta - 576);           qt = 3; }
  const int bi    = b * NN + i;
  const int jbase = qt * 64;
  const int isUp  = qt > (i >> 6);  // block-uniform

  const int t     = threadIdx.x;
  const int lane  = t & 63;
  const int hg    = t >> 6;         // 0..3
  const int q     = lane >> 4;
  const int cc    = lane & 15;

  __shared__ __align__(16) float    xi_s[DD];
  __shared__ __align__(16) _Float16 Af[16384];   // 32 KB: [ksl 0..7][jg][q][cc][e]
  __shared__ float pre_s[HH];       // S_i + b1
  __shared__ float pre2_s[HH];      // T_i + b1 (mirror)
  __shared__ float w2_s[HH];
  __shared__ float sc_s[4][64];

  xi_s[t]   = X[(size_t)bi * DD + t];
  pre_s[t]  = S[(size_t)bi * HH + t] + b1[t];
  pre2_s[t] = T[(size_t)bi * HH + t] + b1[t];
  w2_s[t]   = W2[t];

  const float* __restrict__ Tb = T + (size_t)b * NN * HH;
  const float* __restrict__ Sb = S + (size_t)b * NN * HH;

  const int jloc = t & 63;
  const int jg   = jloc >> 4;
  const int ccw  = jloc & 15;
  const float* __restrict__ xjrow = X + (size_t)(b * NN + jbase + jloc) * DD;

  const char* __restrict__ bsrc = (const char*)Wst + hg * 4096 + (size_t)lane * 16;

  floatx4 a00 = (floatx4)0.f, a01 = (floatx4)0.f, a02 = (floatx4)0.f, a03 = (floatx4)0.f;
  floatx4 a10 = (floatx4)0.f, a11 = (floatx4)0.f, a12 = (floatx4)0.f, a13 = (floatx4)0.f;
  floatx4 a20 = (floatx4)0.f, a21 = (floatx4)0.f, a22 = (floatx4)0.f, a23 = (floatx4)0.f;
  floatx4 a30 = (floatx4)0.f, a31 = (floatx4)0.f, a32 = (floatx4)0.f, a33 = (floatx4)0.f;

#pragma unroll 1
  for (int half = 0; half < 2; ++half) {
    __syncthreads();                 // header ready / prior Af reads done

#pragma unroll
    for (int idx = 0; idx < 8; ++idx) {
      const int ksq = (t >> 6) * 8 + idx;       // local 0..31
      const int d0  = (half * 32 + ksq) * 4;
      const int ksl = ksq >> 2;
      const int qw  = ksq & 3;
      const float4 xi4 = *(const float4*)&xi_s[d0];
      const float4 xj4 = *(const float4*)(xjrow + d0);
      *(half8*)&Af[(ksl * 16 + jg * 4 + qw) * 128 + ccw * 8] = make_afrag(xi4, xj4);
    }
    __syncthreads();                 // Af ready; K-loop below is barrier-free

    const char* bk0 = bsrc + (half * 8) * 16384;
    half8 nb0 = *(const half8*)(bk0);
    half8 nb1 = *(const half8*)(bk0 + 1024);
    half8 nb2 = *(const half8*)(bk0 + 2048);
    half8 nb3 = *(const half8*)(bk0 + 3072);
    const _Float16* ap0 = &Af[lane * 8];
    half8 na0 = *(const half8*)(ap0);
    half8 na1 = *(const half8*)(ap0 + 512);
    half8 na2 = *(const half8*)(ap0 + 1024);
    half8 na3 = *(const half8*)(ap0 + 1536);

#pragma unroll
    for (int ksl = 0; ksl < 8; ++ksl) {
      const half8 cb0 = nb0, cb1 = nb1, cb2 = nb2, cb3 = nb3;
      const half8 ca0 = na0, ca1 = na1, ca2 = na2, ca3 = na3;
      if (ksl < 7) {
        const char* bk = bsrc + (half * 8 + ksl + 1) * 16384;
        nb0 = *(const half8*)(bk);
        nb1 = *(const half8*)(bk + 1024);
        nb2 = *(const half8*)(bk + 2048);
        nb3 = *(const half8*)(bk + 3072);
        const _Float16* ap = &Af[(ksl + 1) * 2048 + lane * 8];
        na0 = *(const half8*)(ap);
        na1 = *(const half8*)(ap + 512);
        na2 = *(const half8*)(ap + 1024);
        na3 = *(const half8*)(ap + 1536);
      }
      MFMA16(ca0, cb0, a00); MFMA16(ca0, cb1, a01); MFMA16(ca0, cb2, a02); MFMA16(ca0, cb3, a03);
      MFMA16(ca1, cb0, a10); MFMA16(ca1, cb1, a11); MFMA16(ca1, cb2, a12); MFMA16(ca1, cb3, a13);
      MFMA16(ca2, cb0, a20); MFMA16(ca2, cb1, a21); MFMA16(ca2, cb2, a22); MFMA16(ca2, cb3, a23);
      MFMA16(ca3, cb0, a30); MFMA16(ca3, cb1, a31); MFMA16(ca3, cb2, a32); MFMA16(ca3, cb3, a33);
    }
  }

  // ---- direct epilogue: H = C + (S_i+b1) + T_j ; silu ; dot w2 ----
  float p00, p01, p02, p03, p10, p11, p12, p13;
  float p20, p21, p22, p23, p30, p31, p32, p33;
  p00=p01=p02=p03=p10=p11=p12=p13=0.f;
  p20=p21=p22=p23=p30=p31=p32=p33=0.f;

#define SILU_DOT(A, r, VROW, PREV, P) { \
    const float tv = VROW[(size_t)(jbase + jj16 + q * 4 + r) * HH + h]; \
    const float hv = A[r] + PREV + tv; \
    const float sv = hv * __builtin_amdgcn_rcpf(1.f + __expf(-hv)); \
    P = fmaf(sv, w2v, P); }

#define EPI_HH(hh, A0, A1, A2, A3, VROW, PRE) { \
    const int h = hg * 64 + hh * 16 + cc; \
    const float w2v = w2_s[h]; \
    const float pv  = PRE[h]; \
    { const int jj16 = 0;  SILU_DOT(A0, 0, VROW, pv, p00) SILU_DOT(A0, 1, VROW, pv, p01) \
                           SILU_DOT(A0, 2, VROW, pv, p02) SILU_DOT(A0, 3, VROW, pv, p03) } \
    { const int jj16 = 16; SILU_DOT(A1, 0, VROW, pv, p10) SILU_DOT(A1, 1, VROW, pv, p11) \
                           SILU_DOT(A1, 2, VROW, pv, p12) SILU_DOT(A1, 3, VROW, pv, p13) } \
    { const int jj16 = 32; SILU_DOT(A2, 0, VROW, pv, p20) SILU_DOT(A2, 1, VROW, pv, p21) \
                           SILU_DOT(A2, 2, VROW, pv, p22) SILU_DOT(A2, 3, VROW, pv, p23) } \
    { const int jj16 = 48; SILU_DOT(A3, 0, VROW, pv, p30) SILU_DOT(A3, 1, VROW, pv, p31) \
                           SILU_DOT(A3, 2, VROW, pv, p32) SILU_DOT(A3, 3, VROW, pv, p33) } }

#define REDW(P, jj, r) { \
    float v = P; \
    v += __shfl_xor(v, 1); v += __shfl_xor(v, 2); \
    v += __shfl_xor(v, 4); v += __shfl_xor(v, 8); \
    if (cc == 0) sc_s[hg][jj * 16 + q * 4 + r] = v; }

#define REDW_ALL \
  REDW(p00, 0, 0) REDW(p01, 0, 1) REDW(p02, 0, 2) REDW(p03, 0, 3) \
  REDW(p10, 1, 0) REDW(p11, 1, 1) REDW(p12, 1, 2) REDW(p13, 1, 3) \
  REDW(p20, 2, 0) REDW(p21, 2, 1) REDW(p22, 2, 2) REDW(p23, 2, 3) \
  REDW(p30, 3, 0) REDW(p31, 3, 1) REDW(p32, 3, 2) REDW(p33, 3, 3)

  EPI_HH(0, a00, a10, a20, a30, Tb, pre_s)
  EPI_HH(1, a01, a11, a21, a31, Tb, pre_s)
  EPI_HH(2, a02, a12, a22, a32, Tb, pre_s)
  EPI_HH(3, a03, a13, a23, a33, Tb, pre_s)
  REDW_ALL
  __syncthreads();

  if (t < 64) {
    float s = sc_s[0][t] + sc_s[1][t] + sc_s[2][t] + sc_s[3][t] + b2[0];
    const int jg2 = jbase + t;
    if (jg2 == i) s = NEGV;
    Sc[(size_t)bi * NN + jg2] = s;
  }

  // ---- mirror epilogue (pure-upper blocks): H' = C + S_j + (T_i+b1) ----
  if (isUp) {
    __syncthreads();                 // sc_s reads done before overwrite
    p00=p01=p02=p03=p10=p11=p12=p13=0.f;
    p20=p21=p22=p23=p30=p31=p32=p33=0.f;
    EPI_HH(0, a00, a10, a20, a30, Sb, pre2_s)
    EPI_HH(1, a01, a11, a21, a31, Sb, pre2_s)
    EPI_HH(2, a02, a12, a22, a32, Sb, pre2_s)
    EPI_HH(3, a03, a13, a23, a33, Sb, pre2_s)
    REDW_ALL
    __syncthreads();
    if (t < 64) {
      const float s = sc_s[0][t] + sc_s[1][t] + sc_s[2][t] + sc_s[3][t] + b2[0];
      Sc[(size_t)(b * NN + jbase + t) * NN + i] = s;   // Sc[j, i]
    }
  }
}

// ---------------- softmax: 1 wave per row, barrier-free ------------------------
// 4 rows/block, float4 load/store, 6+6 shfl_xor reductions, no LDS, no syncs.
__global__ __launch_bounds__(256) void softmax_kernel(const float* __restrict__ Sc,
                                                      float* __restrict__ out) {
  const int w    = threadIdx.x >> 6;        // wave 0..3
  const int lane = threadIdx.x & 63;
  const int bi   = blockIdx.x * 4 + w;      // row 0..1023
  const float4 v = *(const float4*)&Sc[(size_t)bi * NN + lane * 4];
  float m = fmaxf(fmaxf(v.x, v.y), fmaxf(v.z, v.w));
  m = fmaxf(m, __shfl_xor(m, 1));  m = fmaxf(m, __shfl_xor(m, 2));
  m = fmaxf(m, __shfl_xor(m, 4));  m = fmaxf(m, __shfl_xor(m, 8));
  m = fmaxf(m, __shfl_xor(m, 16)); m = fmaxf(m, __shfl_xor(m, 32));
  const float e0 = __expf(v.x - m), e1 = __expf(v.y - m);
  const float e2 = __expf(v.z - m), e3 = __expf(v.w - m);
  float sum = (e0 + e1) + (e2 + e3);
  sum += __shfl_xor(sum, 1);  sum += __shfl_xor(sum, 2);
  sum += __shfl_xor(sum, 4);  sum += __shfl_xor(sum, 8);
  sum += __shfl_xor(sum, 16); sum += __shfl_xor(sum, 32);
  const float r = 1.f / sum;
  float4 o; o.x = e0 * r; o.y = e1 * r; o.z = e2 * r; o.w = e3 * r;
  *(float4*)&out[(size_t)bi * NN + lane * 4] = o;
}

extern "C" void kernel_launch(void* const* d_in, const int* in_sizes, int n_in,
                              void* d_out, int out_size, void* d_ws, size_t ws_size,
                              hipStream_t stream) {
  const float* X  = (const float*)d_in[0];
  const float* W1 = (const float*)d_in[1];
  const float* b1 = (const float*)d_in[2];
  const float* W2 = (const float*)d_in[3];
  const float* b2 = (const float*)d_in[4];
  float* out = (float*)d_out;

  float*     Sws = (float*)d_ws;                             // 1 MB
  float*     Tws = Sws + (size_t)BB * NN * HH;               // 1 MB
  _Float16*  Wst = (_Float16*)(Tws + (size_t)BB * NN * HH);  // 256 KB
  float*     Scw = (float*)(Wst + (size_t)16 * HH * 32);     // 1 MB

  // zero S/T for split-K atomic accumulation (stream op — graph-capture safe)
  hipMemsetAsync(Sws, 0, (size_t)2 * BB * NN * HH * sizeof(float), stream);

  prep_split<<<dim3(512, 4), 256, 0, stream>>>(X, W1, Sws, Tws, Wst);
  score_mfma<<<dim3(640, BB), 256, 0, stream>>>(X, b1, W2, b2, Sws, Tws, Wst, Scw);
  softmax_kernel<<<BB * NN / 4, 256, 0, stream>>>(Scw, out);
}

// Round 3
// 166.358 us; speedup vs baseline: 1.6116x; 1.2304x over previous
//
#include <hip/hip_runtime.h>

#define BB 4
#define NN 256
#define DD 256
#define HH 256
#define NEGV -1.0e9f

typedef _Float16 half8 __attribute__((ext_vector_type(8)));
typedef __fp16   fp16x2 __attribute__((ext_vector_type(2)));
typedef float floatx4 __attribute__((ext_vector_type(4)));

// ---------------- prep (split-K x4): S/T partial projections + wconv -----------
// Grid (512, 4): block (g, kk) -> rows 2g..2g+1, d in [kk*64, kk*64+64).
// 4 fp32 atomic addends per output, order-independent to ~1e-7.
// Wst layout (R13 map): [ks][hgrp][q][cc][e] halves; converted when kk==0,g<256.
__global__ __launch_bounds__(256) void prep_split(const float* __restrict__ X,
                                                  const float* __restrict__ W1,
                                                  float* __restrict__ S,
                                                  float* __restrict__ T,
                                                  _Float16* __restrict__ Wst) {
  const int g  = blockIdx.x;   // 0..511
  const int kk = blockIdx.y;   // 0..3
  const int h  = threadIdx.x;  // 0..255

  if (kk == 0 && g < 256) {    // weight conversion for d = g
    const float wcv = W1[(size_t)(2 * DD + g) * HH + h];
    const float wdv = W1[(size_t)(3 * DD + g) * HH + h];
    const int ks = g >> 4;
    const int dd = g & 15;
    const int q  = dd >> 2;
    const int e  = (dd & 3) * 2;
    const int hgrp = h >> 4;
    const int ccw  = h & 15;
    _Float16* p = Wst + ((size_t)((ks * 16 + hgrp) * 4 + q) * 16 + ccw) * 8 + e;
    p[0] = (_Float16)wcv;
    p[1] = (_Float16)wdv;
  }

  const int row0 = g * 2;
  const int dbase = kk * 64;
  __shared__ float xr[2][64];
  if (h < 64)       xr[0][h]      = X[(size_t)row0 * DD + dbase + h];
  else if (h < 128) xr[1][h - 64] = X[(size_t)(row0 + 1) * DD + dbase + (h - 64)];
  __syncthreads();

  const float* __restrict__ Wa = W1 + (size_t)dbase * HH;
  const float* __restrict__ Wb = W1 + (size_t)(DD + dbase) * HH;
  float sa0 = 0.f, sa1 = 0.f, sb0 = 0.f, sb1 = 0.f;
#pragma unroll 8
  for (int d = 0; d < 64; ++d) {
    const float wa = Wa[(size_t)d * HH + h];
    const float wb = Wb[(size_t)d * HH + h];
    sa0 = fmaf(xr[0][d], wa, sa0);  sb0 = fmaf(xr[0][d], wb, sb0);
    sa1 = fmaf(xr[1][d], wa, sa1);  sb1 = fmaf(xr[1][d], wb, sb1);
  }
  atomicAdd(&S[(size_t)(row0 + 0) * HH + h], sa0);
  atomicAdd(&T[(size_t)(row0 + 0) * HH + h], sb0);
  atomicAdd(&S[(size_t)(row0 + 1) * HH + h], sa1);
  atomicAdd(&T[(size_t)(row0 + 1) * HH + h], sb1);
}

__device__ __forceinline__ half8 make_afrag(const float4 xi, const float4 xj) {
  fp16x2 p0 = __builtin_amdgcn_cvt_pkrtz(__builtin_fabsf(xi.x - xj.x), xi.x * xj.x);
  fp16x2 p1 = __builtin_amdgcn_cvt_pkrtz(__builtin_fabsf(xi.y - xj.y), xi.y * xj.y);
  fp16x2 p2 = __builtin_amdgcn_cvt_pkrtz(__builtin_fabsf(xi.z - xj.z), xi.z * xj.z);
  fp16x2 p3 = __builtin_amdgcn_cvt_pkrtz(__builtin_fabsf(xi.w - xj.w), xi.w * xj.w);
  uint4 u;
  u.x = __builtin_bit_cast(unsigned int, p0);
  u.y = __builtin_bit_cast(unsigned int, p1);
  u.z = __builtin_bit_cast(unsigned int, p2);
  u.w = __builtin_bit_cast(unsigned int, p3);
  return __builtin_bit_cast(half8, u);
}

#define MFMA16(af, bf, acc) acc = __builtin_amdgcn_mfma_f32_16x16x32_f16(af, bf, acc, 0, 0, 0)

// ---------------- score: SYMMETRY-PRUNED pair tiles, 8-wave blocks (R22) -------
// R20/R21 lesson: natural footprint at the 4-wave shape is 112 arch + 64 acc =
// 176 regs -> immovable 2 waves/SIMD; any launch-bounds squeeze spills (R20:
// -48 regs -> 544 MB scratch; R21: -28 -> 191 MB). R22 halves the WAVE tile
// instead: 512 thr/block, each wave 64j x 32h -> acc 32, B-frags 2/kstep
// (2-deep prefetched, ~312cy latency cover), est. ~115 total regs <= 128 =
// 4 waves/SIMD cap. LDS ~38KB -> 2 blocks/CU -> 16 waves/CU (2x round-0).
// Falsifier: WRITE_SIZE > 10 MB means the 128 cap spilled -> abandon this path.
__global__ __launch_bounds__(512, 4) void score_mfma(
    const float* __restrict__ X,  const float* __restrict__ b1,
    const float* __restrict__ W2, const float* __restrict__ b2,
    const float* __restrict__ S,  const float* __restrict__ T,
    const _Float16* __restrict__ Wst, float* __restrict__ Sc) {

  const int beta = blockIdx.x;      // 0..639
  const int b    = blockIdx.y;
  int i, qt;
  if (beta < 256)      { i = beta >> 2;                    qt = beta & 3; }
  else if (beta < 448) { const int g = beta - 256; const int d3 = g / 3;
                         i = 64 + d3;                      qt = 1 + (g - 3 * d3); }
  else if (beta < 576) { const int g = beta - 448;
                         i = 128 + (g >> 1);               qt = 2 + (g & 1); }
  else                 { i = 192 + (beta - 576);           qt = 3; }
  const int bi    = b * NN + i;
  const int jbase = qt * 64;
  const int isUp  = qt > (i >> 6);  // block-uniform

  const int t     = threadIdx.x;    // 0..511
  const int lane  = t & 63;
  const int hg    = t >> 6;         // wave id 0..7 -> h-slice of 32
  const int q     = lane >> 4;
  const int cc    = lane & 15;

  __shared__ __align__(16) float    xi_s[DD];
  __shared__ __align__(16) _Float16 Af[16384];   // 32 KB: [ksl 0..7][jg][qw][ccw][e]
  __shared__ float pre_s[HH];       // S_i + b1
  __shared__ float pre2_s[HH];      // T_i + b1 (mirror)
  __shared__ float w2_s[HH];
  __shared__ float sc_s[8][64];

  if (t < 256) {
    xi_s[t]  = X[(size_t)bi * DD + t];
    pre_s[t] = S[(size_t)bi * HH + t] + b1[t];
  } else {
    const int u = t - 256;
    pre2_s[u] = T[(size_t)bi * HH + u] + b1[u];
    w2_s[u]   = W2[u];
  }

  const float* __restrict__ Tb = T + (size_t)b * NN * HH;
  const float* __restrict__ Sb = S + (size_t)b * NN * HH;

  const int jloc = t & 63;
  const int jg   = jloc >> 4;
  const int ccw  = jloc & 15;
  const float* __restrict__ xjrow = X + (size_t)(b * NN + jbase + jloc) * DD;

  // wave hg covers hgrp = 2*hg .. 2*hg+1 (h = hg*32 .. hg*32+31)
  const char* __restrict__ bsrc = (const char*)Wst + hg * 2048 + (size_t)lane * 16;

  floatx4 a00 = (floatx4)0.f, a01 = (floatx4)0.f;   // [jg][hq]
  floatx4 a10 = (floatx4)0.f, a11 = (floatx4)0.f;
  floatx4 a20 = (floatx4)0.f, a21 = (floatx4)0.f;
  floatx4 a30 = (floatx4)0.f, a31 = (floatx4)0.f;

  // B prefetch, 2-deep across halves (global Wst, barrier-independent)
  half8 Bn0 = *(const half8*)(bsrc);                  // k=0
  half8 Bn1 = *(const half8*)(bsrc + 1024);
  half8 Bm0 = *(const half8*)(bsrc + 16384);          // k=1
  half8 Bm1 = *(const half8*)(bsrc + 16384 + 1024);

#pragma unroll 1
  for (int half = 0; half < 2; ++half) {
    __syncthreads();                 // header ready / prior Af reads done

#pragma unroll
    for (int idx = 0; idx < 4; ++idx) {
      const int ksq = hg * 4 + idx;             // 0..31
      const int d0  = (half * 32 + ksq) * 4;
      const int ksl = ksq >> 2;
      const int qw  = ksq & 3;
      const float4 xi4 = *(const float4*)&xi_s[d0];
      const float4 xj4 = *(const float4*)(xjrow + d0);
      *(half8*)&Af[(ksl * 16 + jg * 4 + qw) * 128 + ccw * 8] = make_afrag(xi4, xj4);
    }
    __syncthreads();                 // Af ready; K-loop below is barrier-free

    const _Float16* ap0 = &Af[lane * 8];
    half8 An0 = *(const half8*)(ap0);
    half8 An1 = *(const half8*)(ap0 + 512);
    half8 An2 = *(const half8*)(ap0 + 1024);
    half8 An3 = *(const half8*)(ap0 + 1536);

#pragma unroll
    for (int ksl = 0; ksl < 8; ++ksl) {
      const half8 Bc0 = Bn0, Bc1 = Bn1;
      Bn0 = Bm0; Bn1 = Bm1;
      const int kg = (half * 8 + ksl + 2) & 15;   // wraps harmlessly at tail
      const char* bk = bsrc + (size_t)kg * 16384;
      Bm0 = *(const half8*)(bk);
      Bm1 = *(const half8*)(bk + 1024);
      const half8 Ac0 = An0, Ac1 = An1, Ac2 = An2, Ac3 = An3;
      if (ksl < 7) {
        const _Float16* ap = &Af[(ksl + 1) * 2048 + lane * 8];
        An0 = *(const half8*)(ap);
        An1 = *(const half8*)(ap + 512);
        An2 = *(const half8*)(ap + 1024);
        An3 = *(const half8*)(ap + 1536);
      }
      MFMA16(Ac0, Bc0, a00); MFMA16(Ac0, Bc1, a01);
      MFMA16(Ac1, Bc0, a10); MFMA16(Ac1, Bc1, a11);
      MFMA16(Ac2, Bc0, a20); MFMA16(Ac2, Bc1, a21);
      MFMA16(Ac3, Bc0, a30); MFMA16(Ac3, Bc1, a31);
    }
  }

  // ---- direct epilogue: H = C + (S_i+b1) + T_j ; silu ; dot w2 ----
  float p00, p01, p02, p03, p10, p11, p12, p13;
  float p20, p21, p22, p23, p30, p31, p32, p33;
  p00=p01=p02=p03=p10=p11=p12=p13=0.f;
  p20=p21=p22=p23=p30=p31=p32=p33=0.f;

#define SILU_DOT(A, r, VROW, PREV, P) { \
    const float tv = VROW[(size_t)(jbase + jj16 + q * 4 + r) * HH + h]; \
    const float hv = A[r] + PREV + tv; \
    const float sv = hv * __builtin_amdgcn_rcpf(1.f + __expf(-hv)); \
    P = fmaf(sv, w2v, P); }

#define EPI_HH(hh, A0, A1, A2, A3, VROW, PRE) { \
    const int h = hg * 32 + hh * 16 + cc; \
    const float w2v = w2_s[h]; \
    const float pv  = PRE[h]; \
    { const int jj16 = 0;  SILU_DOT(A0, 0, VROW, pv, p00) SILU_DOT(A0, 1, VROW, pv, p01) \
                           SILU_DOT(A0, 2, VROW, pv, p02) SILU_DOT(A0, 3, VROW, pv, p03) } \
    { const int jj16 = 16; SILU_DOT(A1, 0, VROW, pv, p10) SILU_DOT(A1, 1, VROW, pv, p11) \
                           SILU_DOT(A1, 2, VROW, pv, p12) SILU_DOT(A1, 3, VROW, pv, p13) } \
    { const int jj16 = 32; SILU_DOT(A2, 0, VROW, pv, p20) SILU_DOT(A2, 1, VROW, pv, p21) \
                           SILU_DOT(A2, 2, VROW, pv, p22) SILU_DOT(A2, 3, VROW, pv, p23) } \
    { const int jj16 = 48; SILU_DOT(A3, 0, VROW, pv, p30) SILU_DOT(A3, 1, VROW, pv, p31) \
                           SILU_DOT(A3, 2, VROW, pv, p32) SILU_DOT(A3, 3, VROW, pv, p33) } }

#define REDW(P, jj, r) { \
    float v = P; \
    v += __shfl_xor(v, 1); v += __shfl_xor(v, 2); \
    v += __shfl_xor(v, 4); v += __shfl_xor(v, 8); \
    if (cc == 0) sc_s[hg][jj * 16 + q * 4 + r] = v; }

#define REDW_ALL \
  REDW(p00, 0, 0) REDW(p01, 0, 1) REDW(p02, 0, 2) REDW(p03, 0, 3) \
  REDW(p10, 1, 0) REDW(p11, 1, 1) REDW(p12, 1, 2) REDW(p13, 1, 3) \
  REDW(p20, 2, 0) REDW(p21, 2, 1) REDW(p22, 2, 2) REDW(p23, 2, 3) \
  REDW(p30, 3, 0) REDW(p31, 3, 1) REDW(p32, 3, 2) REDW(p33, 3, 3)

  EPI_HH(0, a00, a10, a20, a30, Tb, pre_s)
  EPI_HH(1, a01, a11, a21, a31, Tb, pre_s)
  REDW_ALL
  __syncthreads();

  if (t < 64) {
    float s = sc_s[0][t] + sc_s[1][t] + sc_s[2][t] + sc_s[3][t]
            + sc_s[4][t] + sc_s[5][t] + sc_s[6][t] + sc_s[7][t] + b2[0];
    const int jg2 = jbase + t;
    if (jg2 == i) s = NEGV;
    Sc[(size_t)bi * NN + jg2] = s;
  }

  // ---- mirror epilogue (pure-upper blocks): H' = C + S_j + (T_i+b1) ----
  if (isUp) {
    __syncthreads();                 // sc_s reads done before overwrite
    p00=p01=p02=p03=p10=p11=p12=p13=0.f;
    p20=p21=p22=p23=p30=p31=p32=p33=0.f;
    EPI_HH(0, a00, a10, a20, a30, Sb, pre2_s)
    EPI_HH(1, a01, a11, a21, a31, Sb, pre2_s)
    REDW_ALL
    __syncthreads();
    if (t < 64) {
      const float s = sc_s[0][t] + sc_s[1][t] + sc_s[2][t] + sc_s[3][t]
                    + sc_s[4][t] + sc_s[5][t] + sc_s[6][t] + sc_s[7][t] + b2[0];
      Sc[(size_t)(b * NN + jbase + t) * NN + i] = s;   // Sc[j, i]
    }
  }
}

// ---------------- softmax: 1 wave per row, barrier-free ------------------------
// 4 rows/block, float4 load/store, 6+6 shfl_xor reductions, no LDS, no syncs.
__global__ __launch_bounds__(256) void softmax_kernel(const float* __restrict__ Sc,
                                                      float* __restrict__ out) {
  const int w    = threadIdx.x >> 6;        // wave 0..3
  const int lane = threadIdx.x & 63;
  const int bi   = blockIdx.x * 4 + w;      // row 0..1023
  const float4 v = *(const float4*)&Sc[(size_t)bi * NN + lane * 4];
  float m = fmaxf(fmaxf(v.x, v.y), fmaxf(v.z, v.w));
  m = fmaxf(m, __shfl_xor(m, 1));  m = fmaxf(m, __shfl_xor(m, 2));
  m = fmaxf(m, __shfl_xor(m, 4));  m = fmaxf(m, __shfl_xor(m, 8));
  m = fmaxf(m, __shfl_xor(m, 16)); m = fmaxf(m, __shfl_xor(m, 32));
  const float e0 = __expf(v.x - m), e1 = __expf(v.y - m);
  const float e2 = __expf(v.z - m), e3 = __expf(v.w - m);
  float sum = (e0 + e1) + (e2 + e3);
  sum += __shfl_xor(sum, 1);  sum += __shfl_xor(sum, 2);
  sum += __shfl_xor(sum, 4);  sum += __shfl_xor(sum, 8);
  sum += __shfl_xor(sum, 16); sum += __shfl_xor(sum, 32);
  const float r = 1.f / sum;
  float4 o; o.x = e0 * r; o.y = e1 * r; o.z = e2 * r; o.w = e3 * r;
  *(float4*)&out[(size_t)bi * NN + lane * 4] = o;
}

extern "C" void kernel_launch(void* const* d_in, const int* in_sizes, int n_in,
                              void* d_out, int out_size, void* d_ws, size_t ws_size,
                              hipStream_t stream) {
  const float* X  = (const float*)d_in[0];
  const float* W1 = (const float*)d_in[1];
  const float* b1 = (const float*)d_in[2];
  const float* W2 = (const float*)d_in[3];
  const float* b2 = (const float*)d_in[4];
  float* out = (float*)d_out;

  float*     Sws = (float*)d_ws;                             // 1 MB
  float*     Tws = Sws + (size_t)BB * NN * HH;               // 1 MB
  _Float16*  Wst = (_Float16*)(Tws + (size_t)BB * NN * HH);  // 256 KB
  float*     Scw = (float*)(Wst + (size_t)16 * HH * 32);     // 1 MB

  // zero S/T for split-K atomic accumulation (stream op — graph-capture safe)
  hipMemsetAsync(Sws, 0, (size_t)2 * BB * NN * HH * sizeof(float), stream);

  prep_split<<<dim3(512, 4), 256, 0, stream>>>(X, W1, Sws, Tws, Wst);
  score_mfma<<<dim3(640, BB), 512, 0, stream>>>(X, b1, W2, b2, Sws, Tws, Wst, Scw);
  softmax_kernel<<<BB * NN / 4, 256, 0, stream>>>(Scw, out);
}

// Round 4
// 165.994 us; speedup vs baseline: 1.6151x; 1.0022x over previous
//
#include <hip/hip_runtime.h>

#define BB 4
#define NN 256
#define DD 256
#define HH 256
#define NEGV -1.0e9f

typedef _Float16 half8 __attribute__((ext_vector_type(8)));
typedef __fp16   fp16x2 __attribute__((ext_vector_type(2)));
typedef float floatx4 __attribute__((ext_vector_type(4)));

// ---------------- prep (split-K x4): S/T partial projections + wconv -----------
// Grid (512, 4): block (g, kk) -> rows 2g..2g+1, d in [kk*64, kk*64+64).
// 4 fp32 atomic addends per output, order-independent to ~1e-7.
// Wst layout (R13 map): [ks][hgrp][q][cc][e] halves; converted when kk==0,g<256.
__global__ __launch_bounds__(256) void prep_split(const float* __restrict__ X,
                                                  const float* __restrict__ W1,
                                                  float* __restrict__ S,
                                                  float* __restrict__ T,
                                                  _Float16* __restrict__ Wst) {
  const int g  = blockIdx.x;   // 0..511
  const int kk = blockIdx.y;   // 0..3
  const int h  = threadIdx.x;  // 0..255

  if (kk == 0 && g < 256) {    // weight conversion for d = g
    const float wcv = W1[(size_t)(2 * DD + g) * HH + h];
    const float wdv = W1[(size_t)(3 * DD + g) * HH + h];
    const int ks = g >> 4;
    const int dd = g & 15;
    const int q  = dd >> 2;
    const int e  = (dd & 3) * 2;
    const int hgrp = h >> 4;
    const int ccw  = h & 15;
    _Float16* p = Wst + ((size_t)((ks * 16 + hgrp) * 4 + q) * 16 + ccw) * 8 + e;
    p[0] = (_Float16)wcv;
    p[1] = (_Float16)wdv;
  }

  const int row0 = g * 2;
  const int dbase = kk * 64;
  __shared__ float xr[2][64];
  if (h < 64)       xr[0][h]      = X[(size_t)row0 * DD + dbase + h];
  else if (h < 128) xr[1][h - 64] = X[(size_t)(row0 + 1) * DD + dbase + (h - 64)];
  __syncthreads();

  const float* __restrict__ Wa = W1 + (size_t)dbase * HH;
  const float* __restrict__ Wb = W1 + (size_t)(DD + dbase) * HH;
  float sa0 = 0.f, sa1 = 0.f, sb0 = 0.f, sb1 = 0.f;
#pragma unroll 8
  for (int d = 0; d < 64; ++d) {
    const float wa = Wa[(size_t)d * HH + h];
    const float wb = Wb[(size_t)d * HH + h];
    sa0 = fmaf(xr[0][d], wa, sa0);  sb0 = fmaf(xr[0][d], wb, sb0);
    sa1 = fmaf(xr[1][d], wa, sa1);  sb1 = fmaf(xr[1][d], wb, sb1);
  }
  atomicAdd(&S[(size_t)(row0 + 0) * HH + h], sa0);
  atomicAdd(&T[(size_t)(row0 + 0) * HH + h], sb0);
  atomicAdd(&S[(size_t)(row0 + 1) * HH + h], sa1);
  atomicAdd(&T[(size_t)(row0 + 1) * HH + h], sb1);
}

__device__ __forceinline__ half8 make_afrag(const float4 xi, const float4 xj) {
  fp16x2 p0 = __builtin_amdgcn_cvt_pkrtz(__builtin_fabsf(xi.x - xj.x), xi.x * xj.x);
  fp16x2 p1 = __builtin_amdgcn_cvt_pkrtz(__builtin_fabsf(xi.y - xj.y), xi.y * xj.y);
  fp16x2 p2 = __builtin_amdgcn_cvt_pkrtz(__builtin_fabsf(xi.z - xj.z), xi.z * xj.z);
  fp16x2 p3 = __builtin_amdgcn_cvt_pkrtz(__builtin_fabsf(xi.w - xj.w), xi.w * xj.w);
  uint4 u;
  u.x = __builtin_bit_cast(unsigned int, p0);
  u.y = __builtin_bit_cast(unsigned int, p1);
  u.z = __builtin_bit_cast(unsigned int, p2);
  u.w = __builtin_bit_cast(unsigned int, p3);
  return __builtin_bit_cast(half8, u);
}

#define MFMA16(af, bf, acc) acc = __builtin_amdgcn_mfma_f32_16x16x32_f16(af, bf, acc, 0, 0, 0)

// ---------------- score: symmetry-pruned pair tiles, phase-fused (R23) ---------
// R22 lesson: occupancy 2x (19->37%) changed nothing -> not TLP-bound; bound by
// correlated phase stalls + shallow per-thread MLP (compiler used only 56/128
// VGPRs). R23: (1) stage BOTH K-halves upfront (Af 64KB, barriers 4->2,
// seamless 16-step K-loop); (2) epilogue loads hoisted 32-deep into registers
// before silu math. FP order unchanged -> absmax must stay 3.05e-5 exactly.
// Falsifier: WRITE_SIZE > 10 MB = spill (cap 128 regs at (512,4)).
__global__ __launch_bounds__(512, 4) void score_mfma(
    const float* __restrict__ X,  const float* __restrict__ b1,
    const float* __restrict__ W2, const float* __restrict__ b2,
    const float* __restrict__ S,  const float* __restrict__ T,
    const _Float16* __restrict__ Wst, float* __restrict__ Sc) {

  const int beta = blockIdx.x;      // 0..639
  const int b    = blockIdx.y;
  int i, qt;
  if (beta < 256)      { i = beta >> 2;                    qt = beta & 3; }
  else if (beta < 448) { const int g = beta - 256; const int d3 = g / 3;
                         i = 64 + d3;                      qt = 1 + (g - 3 * d3); }
  else if (beta < 576) { const int g = beta - 448;
                         i = 128 + (g >> 1);               qt = 2 + (g & 1); }
  else                 { i = 192 + (beta - 576);           qt = 3; }
  const int bi    = b * NN + i;
  const int jbase = qt * 64;
  const int isUp  = qt > (i >> 6);  // block-uniform

  const int t     = threadIdx.x;    // 0..511
  const int lane  = t & 63;
  const int hg    = t >> 6;         // wave id 0..7 -> h-slice of 32
  const int q     = lane >> 4;
  const int cc    = lane & 15;

  __shared__ __align__(16) float    xi_s[DD];
  __shared__ __align__(16) _Float16 Af[32768];   // 64 KB: [kg 0..15][jg][qw][ccw][e]
  __shared__ float pre_s[HH];       // S_i + b1
  __shared__ float pre2_s[HH];      // T_i + b1 (mirror)
  __shared__ float w2_s[HH];
  __shared__ float sc_s[8][64];

  if (t < 256) {
    xi_s[t]  = X[(size_t)bi * DD + t];
    pre_s[t] = S[(size_t)bi * HH + t] + b1[t];
  } else {
    const int u = t - 256;
    pre2_s[u] = T[(size_t)bi * HH + u] + b1[u];
    w2_s[u]   = W2[u];
  }

  const float* __restrict__ Tb = T + (size_t)b * NN * HH;
  const float* __restrict__ Sb = S + (size_t)b * NN * HH;

  const int jloc = t & 63;
  const int jg   = jloc >> 4;
  const int ccw  = jloc & 15;
  const float* __restrict__ xjrow = X + (size_t)(b * NN + jbase + jloc) * DD;

  // wave hg covers hgrp pair 2hg..2hg+1 (h = hg*32 .. hg*32+31)
  const char* __restrict__ bsrc = (const char*)Wst + hg * 2048 + (size_t)lane * 16;

  __syncthreads();                  // header (xi_s) ready

  // ---- stage full K (both halves) in one pass: 8 frags/thread, 8 loads MLP ----
  {
    const int sgrp = t >> 6;
#pragma unroll
    for (int idx = 0; idx < 8; ++idx) {
      const int ksqg = sgrp * 8 + idx;          // 0..63 k-quads
      const int d0   = ksqg * 4;
      const int kg   = ksqg >> 2;               // 0..15
      const int qw   = ksqg & 3;
      const float4 xi4 = *(const float4*)&xi_s[d0];
      const float4 xj4 = *(const float4*)(xjrow + d0);
      *(half8*)&Af[kg * 2048 + (jg * 4 + qw) * 128 + ccw * 8] = make_afrag(xi4, xj4);
    }
  }
  __syncthreads();                  // Af ready; K-loop barrier-free, 16 steps

  floatx4 acc0[4], acc1[4];         // [jj] for the wave's 2 h-16 groups
#pragma unroll
  for (int u = 0; u < 4; ++u) { acc0[u] = (floatx4)0.f; acc1[u] = (floatx4)0.f; }

  // B 2-deep prefetch (global Wst), A 1-ahead (LDS)
  half8 Bf0[2], Bf1[2];
#pragma unroll
  for (int u = 0; u < 2; ++u) {
    Bf0[u] = *(const half8*)(bsrc + (size_t)u * 16384);
    Bf1[u] = *(const half8*)(bsrc + (size_t)u * 16384 + 1024);
  }
  const _Float16* ap0 = &Af[lane * 8];
  half8 An0 = *(const half8*)(ap0);
  half8 An1 = *(const half8*)(ap0 + 512);
  half8 An2 = *(const half8*)(ap0 + 1024);
  half8 An3 = *(const half8*)(ap0 + 1536);

#pragma unroll
  for (int kg = 0; kg < 16; ++kg) {
    const int s = kg & 1;                       // static under full unroll
    const half8 Bc0 = Bf0[s], Bc1 = Bf1[s];
    const half8 Ac0 = An0, Ac1 = An1, Ac2 = An2, Ac3 = An3;
    if (kg < 14) {
      const char* bk = bsrc + (size_t)(kg + 2) * 16384;
      Bf0[s] = *(const half8*)(bk);
      Bf1[s] = *(const half8*)(bk + 1024);
    }
    if (kg < 15) {
      const _Float16* ap = &Af[(kg + 1) * 2048 + lane * 8];
      An0 = *(const half8*)(ap);
      An1 = *(const half8*)(ap + 512);
      An2 = *(const half8*)(ap + 1024);
      An3 = *(const half8*)(ap + 1536);
    }
    MFMA16(Ac0, Bc0, acc0[0]); MFMA16(Ac0, Bc1, acc1[0]);
    MFMA16(Ac1, Bc0, acc0[1]); MFMA16(Ac1, Bc1, acc1[1]);
    MFMA16(Ac2, Bc0, acc0[2]); MFMA16(Ac2, Bc1, acc1[2]);
    MFMA16(Ac3, Bc0, acc0[3]); MFMA16(Ac3, Bc1, acc1[3]);
  }

  // ---- epilogues: loads hoisted 32-deep, then silu+dot, then wave-reduce ----
  const int h0   = hg * 32 + cc;
  const int h1   = h0 + 16;
  const int jrow = jbase + q * 4;

#define EPILOGUE(VROW, PRE) {                                                   \
    float tv0[16], tv1[16];                                                     \
    _Pragma("unroll")                                                           \
    for (int u = 0; u < 16; ++u) {                                              \
      const size_t j = (size_t)(jrow + (u >> 2) * 16 + (u & 3)) * HH;           \
      tv0[u] = VROW[j + h0];                                                    \
      tv1[u] = VROW[j + h1];                                                    \
    }                                                                           \
    const float w20 = w2_s[h0], pv0 = PRE[h0];                                  \
    const float w21 = w2_s[h1], pv1 = PRE[h1];                                  \
    float p[16];                                                                \
    _Pragma("unroll")                                                           \
    for (int u = 0; u < 16; ++u) {                                              \
      const float hv0 = acc0[u >> 2][u & 3] + pv0 + tv0[u];                     \
      const float sv0 = hv0 * __builtin_amdgcn_rcpf(1.f + __expf(-hv0));        \
      p[u] = sv0 * w20;                                                         \
      const float hv1 = acc1[u >> 2][u & 3] + pv1 + tv1[u];                     \
      const float sv1 = hv1 * __builtin_amdgcn_rcpf(1.f + __expf(-hv1));        \
      p[u] = fmaf(sv1, w21, p[u]);                                              \
    }                                                                           \
    _Pragma("unroll")                                                           \
    for (int u = 0; u < 16; ++u) {                                              \
      float v = p[u];                                                           \
      v += __shfl_xor(v, 1); v += __shfl_xor(v, 2);                             \
      v += __shfl_xor(v, 4); v += __shfl_xor(v, 8);                             \
      if (cc == 0) sc_s[hg][(u >> 2) * 16 + q * 4 + (u & 3)] = v;               \
    } }

  // direct: H = C + (S_i+b1) + T_j
  EPILOGUE(Tb, pre_s)
  __syncthreads();

  if (t < 64) {
    float s = sc_s[0][t] + sc_s[1][t] + sc_s[2][t] + sc_s[3][t]
            + sc_s[4][t] + sc_s[5][t] + sc_s[6][t] + sc_s[7][t] + b2[0];
    const int jg2 = jbase + t;
    if (jg2 == i) s = NEGV;
    Sc[(size_t)bi * NN + jg2] = s;
  }

  // mirror (pure-upper blocks): H' = C + S_j + (T_i+b1)
  if (isUp) {
    __syncthreads();                // sc_s reads done before overwrite
    EPILOGUE(Sb, pre2_s)
    __syncthreads();
    if (t < 64) {
      const float s = sc_s[0][t] + sc_s[1][t] + sc_s[2][t] + sc_s[3][t]
                    + sc_s[4][t] + sc_s[5][t] + sc_s[6][t] + sc_s[7][t] + b2[0];
      Sc[(size_t)(b * NN + jbase + t) * NN + i] = s;   // Sc[j, i]
    }
  }
#undef EPILOGUE
}

// ---------------- softmax: 1 wave per row, barrier-free ------------------------
// 4 rows/block, float4 load/store, 6+6 shfl_xor reductions, no LDS, no syncs.
__global__ __launch_bounds__(256) void softmax_kernel(const float* __restrict__ Sc,
                                                      float* __restrict__ out) {
  const int w    = threadIdx.x >> 6;        // wave 0..3
  const int lane = threadIdx.x & 63;
  const int bi   = blockIdx.x * 4 + w;      // row 0..1023
  const float4 v = *(const float4*)&Sc[(size_t)bi * NN + lane * 4];
  float m = fmaxf(fmaxf(v.x, v.y), fmaxf(v.z, v.w));
  m = fmaxf(m, __shfl_xor(m, 1));  m = fmaxf(m, __shfl_xor(m, 2));
  m = fmaxf(m, __shfl_xor(m, 4));  m = fmaxf(m, __shfl_xor(m, 8));
  m = fmaxf(m, __shfl_xor(m, 16)); m = fmaxf(m, __shfl_xor(m, 32));
  const float e0 = __expf(v.x - m), e1 = __expf(v.y - m);
  const float e2 = __expf(v.z - m), e3 = __expf(v.w - m);
  float sum = (e0 + e1) + (e2 + e3);
  sum += __shfl_xor(sum, 1);  sum += __shfl_xor(sum, 2);
  sum += __shfl_xor(sum, 4);  sum += __shfl_xor(sum, 8);
  sum += __shfl_xor(sum, 16); sum += __shfl_xor(sum, 32);
  const float r = 1.f / sum;
  float4 o; o.x = e0 * r; o.y = e1 * r; o.z = e2 * r; o.w = e3 * r;
  *(float4*)&out[(size_t)bi * NN + lane * 4] = o;
}

extern "C" void kernel_launch(void* const* d_in, const int* in_sizes, int n_in,
                              void* d_out, int out_size, void* d_ws, size_t ws_size,
                              hipStream_t stream) {
  const float* X  = (const float*)d_in[0];
  const float* W1 = (const float*)d_in[1];
  const float* b1 = (const float*)d_in[2];
  const float* W2 = (const float*)d_in[3];
  const float* b2 = (const float*)d_in[4];
  float* out = (float*)d_out;

  float*     Sws = (float*)d_ws;                             // 1 MB
  float*     Tws = Sws + (size_t)BB * NN * HH;               // 1 MB
  _Float16*  Wst = (_Float16*)(Tws + (size_t)BB * NN * HH);  // 256 KB
  float*     Scw = (float*)(Wst + (size_t)16 * HH * 32);     // 1 MB

  // zero S/T for split-K atomic accumulation (stream op — graph-capture safe)
  hipMemsetAsync(Sws, 0, (size_t)2 * BB * NN * HH * sizeof(float), stream);

  prep_split<<<dim3(512, 4), 256, 0, stream>>>(X, W1, Sws, Tws, Wst);
  score_mfma<<<dim3(640, BB), 512, 0, stream>>>(X, b1, W2, b2, Sws, Tws, Wst, Scw);
  softmax_kernel<<<BB * NN / 4, 256, 0, stream>>>(Scw, out);
}